// Round 9
// baseline (44.891 us; speedup 1.0000x reference)
//
#include <hip/hip_runtime.h>
#include <math.h>

#define S_ 4
#define NLAB 16
#define C1 32
#define C2 64
#define N_ 512
#define RC 6.0f
#define PI_OVER_RC 0.5235987755982988f  // pi/6
#define NBMAX 96                        // divisible by 8; nn mean ~30, safe cap
#define REPS 4   // DIAGNOSTIC: repeat computation -> counters visible + F/R decomposition

// 1 wave = 1 atom. 4 atoms/block. Grid 512 blocks.
__global__ __launch_bounds__(256, 2) void desc_kernel(
    const int* __restrict__ numbers,    // [B,N]
    const float* __restrict__ coords,   // [B,N,3]
    const float* __restrict__ nuww0, const float* __restrict__ sigmas0,
    const float* __restrict__ centres0, // [16,32]
    const float* __restrict__ nuww1, const float* __restrict__ sigmas1,
    const float* __restrict__ centres1, // [16,64]
    float* __restrict__ out)            // [B,N,4096]
{
    __shared__ float s_c0[NLAB * 33];        // stride-33: conflict-free
    __shared__ float s_c1[NLAB * C2];
    __shared__ float s_ww0[NLAB], s_sg0[NLAB], s_ww1[NLAB], s_sg1[NLAB];
    __shared__ float4 s_pair[4][NBMAX];      // scan:(dx,dy,dz,d) -> passB:(fc,ax,ay,az)
    __shared__ float  s_s1[4][NBMAX];
    __shared__ int    s_lab[4][NBMAX];
    __shared__ float4 s_Lm[4][C2];

    const int tid  = threadIdx.x;
    const int w    = tid >> 6;
    const int lane = tid & 63;
    const int bi   = blockIdx.x * 4 + w;     // b*N + i
    const int b    = bi >> 9;
    const int i    = bi & (N_ - 1);
    const int base = b * N_;

    for (int idx = tid; idx < NLAB * C1; idx += 256) {
        int l = idx >> 5, c = idx & 31;
        s_c0[l * 33 + c] = centres0[idx];
    }
    for (int idx = tid; idx < NLAB * C2; idx += 256) s_c1[idx] = centres1[idx];
    if (tid < NLAB) {
        s_ww0[tid] = nuww0[tid]; s_sg0[tid] = sigmas0[tid];
        s_ww1[tid] = nuww1[tid]; s_sg1[tid] = sigmas1[tid];
    }
    __syncthreads();                          // only block-wide barrier

    #pragma unroll 1
    for (int rep = 0; rep < REPS; ++rep) {
        asm volatile("" ::: "memory");        // forbid CSE across reps

        const float xi = coords[(base + i) * 3 + 0];
        const float yi = coords[(base + i) * 3 + 1];
        const float zi = coords[(base + i) * 3 + 2];
        const int zlab = numbers[base + i] * S_;

        // ---- scan: ballot compaction (j-order preserved, deterministic) ----
        int cnt = 0;
        #pragma unroll
        for (int t = 0; t < 8; ++t) {
            int j = t * 64 + lane;
            float dx = coords[(base + j) * 3 + 0] - xi;
            float dy = coords[(base + j) * 3 + 1] - yi;
            float dz = coords[(base + j) * 3 + 2] - zi;
            int   zj = numbers[base + j];     // hoisted out of divergent branch
            float d2 = dx * dx + dy * dy + dz * dz;
            float d  = sqrtf(d2);             // match ref: test rounded d
            bool hit = (j != i) && (d <= RC);
            unsigned long long m = __ballot(hit);
            int slot = cnt + __popcll(m & ((1ull << lane) - 1ull));
            if (hit && slot < NBMAX) {
                s_pair[w][slot] = make_float4(dx, dy, dz, d);
                s_lab[w][slot]  = zlab + zj;
            }
            cnt += __popcll(m);
        }
        const int nn  = min(cnt, NBMAX);
        const int nnp = (nn + 7) & ~7;        // ≤ NBMAX (96 divisible by 8)
        // zero-pad so phase 2 can run a fixed-unroll loop; p * 0 == 0
        for (int k = nn + lane; k < nnp; k += 64) {
            s_pair[w][k] = make_float4(0.f, 0.f, 0.f, 0.f);
            s_lab[w][k]  = 0;
            s_s1[w][k]   = 0.f;
        }
        __builtin_amdgcn_wave_barrier();

        // ---- pass B: lane-per-pair, layer-0 scalar + raij (4 indep exp chains) ----
        for (int k = lane; k < nn; k += 64) {
            float4 g  = s_pair[w][k];
            int   lab = s_lab[w][k];
            float fc  = 0.5f * __cosf(g.w * PI_OVER_RC) + 0.5f;
            float sg0 = s_sg0[lab];
            const float* c0 = &s_c0[lab * 33];
            float p0 = 0.f, p1 = 0.f, p2 = 0.f, p3 = 0.f;
            #pragma unroll
            for (int c = 0; c < C1; c += 4) {
                float a0 = (fc - c0[c])     * sg0;
                float a1 = (fc - c0[c + 1]) * sg0;
                float a2 = (fc - c0[c + 2]) * sg0;
                float a3 = (fc - c0[c + 3]) * sg0;
                p0 += __expf(-(a0 * a0));
                p1 += __expf(-(a1 * a1));
                p2 += __expf(-(a2 * a2));
                p3 += __expf(-(a3 * a3));
            }
            float fac = (g.w > 0.f) ? (fc / g.w) : 0.f;
            s_pair[w][k] = make_float4(fc, g.x * fac, g.y * fac, g.z * fac);
            s_s1[w][k]   = s_ww0[lab] * ((p0 + p1) + (p2 + p3));
        }
        __builtin_amdgcn_wave_barrier();

        // ---- phase 2: lane = channel; 8-wide unrolled batches (indep LDS chains) ----
        float a0 = 0.f, a1 = 0.f, a2 = 0.f, a3 = 0.f;
        for (int k0 = 0; k0 < nnp; k0 += 8) {
            #pragma unroll
            for (int u = 0; u < 8; ++u) {
                int    k   = k0 + u;
                int    lab = s_lab[w][k];
                float  s1  = s_s1[w][k];
                float4 r4  = s_pair[w][k];
                float  al  = (s1 - s_c1[lab * C2 + lane]) * s_sg1[lab];
                float  p   = s_ww1[lab] * __expf(-(al * al));
                a0 += p * r4.x; a1 += p * r4.y; a2 += p * r4.z; a3 += p * r4.w;
            }
        }
        s_Lm[w][lane] = make_float4(a0, a1, a2, a3);
        __builtin_amdgcn_wave_barrier();

        // ---- ||R||_F^2 = ||L^T L||_F^2 via 4x4 Gram wave-reduce ----
        float g00 = a0 * a0, g01 = a0 * a1, g02 = a0 * a2, g03 = a0 * a3;
        float g11 = a1 * a1, g12 = a1 * a2, g13 = a1 * a3;
        float g22 = a2 * a2, g23 = a2 * a3, g33 = a3 * a3;
        #pragma unroll
        for (int off = 32; off >= 1; off >>= 1) {
            g00 += __shfl_xor(g00, off, 64); g01 += __shfl_xor(g01, off, 64);
            g02 += __shfl_xor(g02, off, 64); g03 += __shfl_xor(g03, off, 64);
            g11 += __shfl_xor(g11, off, 64); g12 += __shfl_xor(g12, off, 64);
            g13 += __shfl_xor(g13, off, 64); g22 += __shfl_xor(g22, off, 64);
            g23 += __shfl_xor(g23, off, 64); g33 += __shfl_xor(g33, off, 64);
        }
        float ss = g00 * g00 + g11 * g11 + g22 * g22 + g33 * g33
                 + 2.f * (g01 * g01 + g02 * g02 + g03 * g03
                        + g12 * g12 + g13 * g13 + g23 * g23);
        float inv = rsqrtf(ss);               // ss==0 -> NaN, same as ref 0/0

        // ---- compute R + store (dwordx4, coalesced); fold inv into Lc ----
        float4 Lc0_ = s_Lm[w][(lane & 15) * 4 + 0];
        float4 Lc1_ = s_Lm[w][(lane & 15) * 4 + 1];
        float4 Lc2_ = s_Lm[w][(lane & 15) * 4 + 2];
        float4 Lc3_ = s_Lm[w][(lane & 15) * 4 + 3];
        Lc0_.x *= inv; Lc0_.y *= inv; Lc0_.z *= inv; Lc0_.w *= inv;
        Lc1_.x *= inv; Lc1_.y *= inv; Lc1_.z *= inv; Lc1_.w *= inv;
        Lc2_.x *= inv; Lc2_.y *= inv; Lc2_.z *= inv; Lc2_.w *= inv;
        Lc3_.x *= inv; Lc3_.y *= inv; Lc3_.z *= inv; Lc3_.w *= inv;
        float* po = out + (size_t)bi * (C2 * C2);
        #pragma unroll
        for (int q = 0; q < 16; ++q) {
            int dd = q * 4 + (lane >> 4);
            float4 Ld = s_Lm[w][dd];
            float4 v;
            v.x = Lc0_.x * Ld.x + Lc0_.y * Ld.y + Lc0_.z * Ld.z + Lc0_.w * Ld.w;
            v.y = Lc1_.x * Ld.x + Lc1_.y * Ld.y + Lc1_.z * Ld.z + Lc1_.w * Ld.w;
            v.z = Lc2_.x * Ld.x + Lc2_.y * Ld.y + Lc2_.z * Ld.z + Lc2_.w * Ld.w;
            v.w = Lc3_.x * Ld.x + Lc3_.y * Ld.y + Lc3_.z * Ld.z + Lc3_.w * Ld.w;
            *reinterpret_cast<float4*>(po + q * 256 + lane * 4) = v;
        }
        __builtin_amdgcn_wave_barrier();
    }
}

extern "C" void kernel_launch(void* const* d_in, const int* in_sizes, int n_in,
                              void* d_out, int out_size, void* d_ws, size_t ws_size,
                              hipStream_t stream) {
    const int*   numbers  = (const int*)  d_in[1];
    const float* coords   = (const float*)d_in[2];
    const float* nuww0    = (const float*)d_in[3];
    const float* sigmas0  = (const float*)d_in[4];
    const float* centres0 = (const float*)d_in[5];
    const float* nuww1    = (const float*)d_in[6];
    const float* sigmas1  = (const float*)d_in[7];
    const float* centres1 = (const float*)d_in[8];
    float* out = (float*)d_out;

    const int B = in_sizes[1] / N_;           // 4
    dim3 grid(B * N_ / 4), block(256);        // 4 atoms per block (1 per wave)
    desc_kernel<<<grid, block, 0, stream>>>(numbers, coords, nuww0, sigmas0,
                                            centres0, nuww1, sigmas1, centres1, out);
}

// Round 10
// 22.281 us; speedup vs baseline: 2.0147x; 2.0147x over previous
//
#include <hip/hip_runtime.h>
#include <math.h>

#define S_ 4
#define NLAB 16
#define C1 32
#define C2 64
#define N_ 512
#define RC 6.0f
#define PI_OVER_RC 0.5235987755982988f  // pi/6
#define SEGCAP 32   // per-wave segment cap; per-quarter nn ~ Binom(nn,1/4), mean ~9, cap +7sigma

// 1 block = 1 atom, 4 waves each own a j-quarter. Grid 2048 = 8 blocks/CU (full occupancy).
__global__ __launch_bounds__(256, 8) void desc_kernel(
    const int* __restrict__ numbers,    // [B,N]
    const float* __restrict__ coords,   // [B,N,3]
    const float* __restrict__ nuww0, const float* __restrict__ sigmas0,
    const float* __restrict__ centres0, // [16,32]
    const float* __restrict__ nuww1, const float* __restrict__ sigmas1,
    const float* __restrict__ centres1, // [16,64]
    float* __restrict__ out)            // [B,N,4096]
{
    __shared__ float s_c0[NLAB * 33];        // stride-33: conflict-free
    __shared__ float s_c1[NLAB * C2];
    __shared__ float s_ww0[NLAB], s_sg0[NLAB], s_ww1[NLAB], s_sg1[NLAB];
    __shared__ float4 s_pair[4][SEGCAP];     // per-wave segment: (dx,dy,dz,d) -> (fc,ax,ay,az)
    __shared__ float  s_s1[4][SEGCAP];
    __shared__ int    s_lab[4][SEGCAP];
    __shared__ float4 s_part[4][C2];         // per-wave partial Lm
    __shared__ float4 s_Lm[C2];              // combined (same-value writes from all waves)

    const int tid  = threadIdx.x;
    const int wq   = tid >> 6;               // wave 0..3 = j-quarter
    const int lane = tid & 63;
    const int bi   = blockIdx.x;             // b*N + i
    const int b    = bi >> 9;
    const int i    = bi & (N_ - 1);
    const int base = b * N_;

    // ---- stage params ----
    for (int idx = tid; idx < NLAB * C1; idx += 256) {
        int l = idx >> 5, c = idx & 31;
        s_c0[l * 33 + c] = centres0[idx];
    }
    for (int idx = tid; idx < NLAB * C2; idx += 256) s_c1[idx] = centres1[idx];
    if (tid < NLAB) {
        s_ww0[tid] = nuww0[tid]; s_sg0[tid] = sigmas0[tid];
        s_ww1[tid] = nuww1[tid]; s_sg1[tid] = sigmas1[tid];
    }
    __syncthreads();

    const float xi = coords[(base + i) * 3 + 0];
    const float yi = coords[(base + i) * 3 + 1];
    const float zi = coords[(base + i) * 3 + 2];
    const int zlab = numbers[base + i] * S_;

    // ---- scan own j-quarter, ballot-compact into own segment ----
    int cntq = 0;
    #pragma unroll
    for (int t = 0; t < 2; ++t) {
        int j = wq * 128 + t * 64 + lane;
        float dx = coords[(base + j) * 3 + 0] - xi;
        float dy = coords[(base + j) * 3 + 1] - yi;
        float dz = coords[(base + j) * 3 + 2] - zi;
        int   zj = numbers[base + j];
        float d2 = dx * dx + dy * dy + dz * dz;
        float d  = sqrtf(d2);                // match ref: test rounded d
        bool hit = (j != i) && (d <= RC);
        unsigned long long m = __ballot(hit);
        int slot = cntq + __popcll(m & ((1ull << lane) - 1ull));
        if (hit && slot < SEGCAP) {
            s_pair[wq][slot] = make_float4(dx, dy, dz, d);
            s_lab[wq][slot]  = zlab + zj;
        }
        cntq += __popcll(m);
    }
    const int nnq = min(cntq, SEGCAP);
    __builtin_amdgcn_wave_barrier();

    // ---- pass B: lane-per-pair on own segment (nnq <= 32 -> single step) ----
    if (lane < nnq) {
        int   k   = lane;
        float4 g  = s_pair[wq][k];
        int   lab = s_lab[wq][k];
        float fc  = 0.5f * __cosf(g.w * PI_OVER_RC) + 0.5f;
        float sg0 = s_sg0[lab];
        const float* c0 = &s_c0[lab * 33];
        float p0 = 0.f, p1 = 0.f;
        #pragma unroll
        for (int c = 0; c < C1; c += 2) {
            float a0 = (fc - c0[c])     * sg0;
            float a1 = (fc - c0[c + 1]) * sg0;
            p0 += __expf(-(a0 * a0));
            p1 += __expf(-(a1 * a1));
        }
        float fac = (g.w > 0.f) ? (fc / g.w) : 0.f;
        s_pair[wq][k] = make_float4(fc, g.x * fac, g.y * fac, g.z * fac);
        s_s1[wq][k]   = s_ww0[lab] * (p0 + p1);
    }
    __builtin_amdgcn_wave_barrier();

    // ---- phase 2: lane = channel; iterate own segment (~8 iters avg) ----
    {
        float a0 = 0.f, a1 = 0.f, a2 = 0.f, a3 = 0.f;
        for (int k = 0; k < nnq; ++k) {
            int    lab = s_lab[wq][k];       // broadcast
            float  s1  = s_s1[wq][k];        // broadcast
            float4 r4  = s_pair[wq][k];      // broadcast
            float  al  = (s1 - s_c1[lab * C2 + lane]) * s_sg1[lab];
            float  p   = s_ww1[lab] * __expf(-(al * al));
            a0 += p * r4.x; a1 += p * r4.y; a2 += p * r4.z; a3 += p * r4.w;
        }
        s_part[wq][lane] = make_float4(a0, a1, a2, a3);
    }
    __syncthreads();                          // partials visible block-wide

    // ---- combine partials (every wave, redundant -> no further block sync) ----
    float4 P0 = s_part[0][lane], P1 = s_part[1][lane];
    float4 P2 = s_part[2][lane], P3 = s_part[3][lane];
    float a0 = (P0.x + P1.x) + (P2.x + P3.x);
    float a1 = (P0.y + P1.y) + (P2.y + P3.y);
    float a2 = (P0.z + P1.z) + (P2.z + P3.z);
    float a3 = (P0.w + P1.w) + (P2.w + P3.w);
    s_Lm[lane] = make_float4(a0, a1, a2, a3); // all waves write identical values (benign)

    // ---- ||R||_F^2 = ||L^T L||_F^2 via 4x4 Gram wave-reduce (per wave) ----
    float g00 = a0 * a0, g01 = a0 * a1, g02 = a0 * a2, g03 = a0 * a3;
    float g11 = a1 * a1, g12 = a1 * a2, g13 = a1 * a3;
    float g22 = a2 * a2, g23 = a2 * a3, g33 = a3 * a3;
    #pragma unroll
    for (int off = 32; off >= 1; off >>= 1) {
        g00 += __shfl_xor(g00, off, 64); g01 += __shfl_xor(g01, off, 64);
        g02 += __shfl_xor(g02, off, 64); g03 += __shfl_xor(g03, off, 64);
        g11 += __shfl_xor(g11, off, 64); g12 += __shfl_xor(g12, off, 64);
        g13 += __shfl_xor(g13, off, 64); g22 += __shfl_xor(g22, off, 64);
        g23 += __shfl_xor(g23, off, 64); g33 += __shfl_xor(g33, off, 64);
    }
    float ss = g00 * g00 + g11 * g11 + g22 * g22 + g33 * g33
             + 2.f * (g01 * g01 + g02 * g02 + g03 * g03
                    + g12 * g12 + g13 * g13 + g23 * g23);
    float inv = rsqrtf(ss);                   // ss==0 -> NaN, same as ref 0/0
    __builtin_amdgcn_wave_barrier();          // own s_Lm writes ordered before reads

    // ---- epilogue: wave wq writes rows [wq*16, wq*16+16) = 4 KB, coalesced ----
    const int cb = (lane & 15) * 4;
    float4 Lc0 = s_Lm[cb + 0], Lc1 = s_Lm[cb + 1];
    float4 Lc2 = s_Lm[cb + 2], Lc3 = s_Lm[cb + 3];
    Lc0.x *= inv; Lc0.y *= inv; Lc0.z *= inv; Lc0.w *= inv;
    Lc1.x *= inv; Lc1.y *= inv; Lc1.z *= inv; Lc1.w *= inv;
    Lc2.x *= inv; Lc2.y *= inv; Lc2.z *= inv; Lc2.w *= inv;
    Lc3.x *= inv; Lc3.y *= inv; Lc3.z *= inv; Lc3.w *= inv;
    float* po = out + (size_t)bi * (C2 * C2);
    #pragma unroll
    for (int t = 0; t < 4; ++t) {
        int q  = wq * 4 + t;                  // chunk of 256 elements (4 rows)
        int dd = q * 4 + (lane >> 4);
        float4 Ld = s_Lm[dd];                 // multicast
        float4 v;
        v.x = Lc0.x * Ld.x + Lc0.y * Ld.y + Lc0.z * Ld.z + Lc0.w * Ld.w;
        v.y = Lc1.x * Ld.x + Lc1.y * Ld.y + Lc1.z * Ld.z + Lc1.w * Ld.w;
        v.z = Lc2.x * Ld.x + Lc2.y * Ld.y + Lc2.z * Ld.z + Lc2.w * Ld.w;
        v.w = Lc3.x * Ld.x + Lc3.y * Ld.y + Lc3.z * Ld.z + Lc3.w * Ld.w;
        *reinterpret_cast<float4*>(po + q * 256 + lane * 4) = v;
    }
}

extern "C" void kernel_launch(void* const* d_in, const int* in_sizes, int n_in,
                              void* d_out, int out_size, void* d_ws, size_t ws_size,
                              hipStream_t stream) {
    const int*   numbers  = (const int*)  d_in[1];
    const float* coords   = (const float*)d_in[2];
    const float* nuww0    = (const float*)d_in[3];
    const float* sigmas0  = (const float*)d_in[4];
    const float* centres0 = (const float*)d_in[5];
    const float* nuww1    = (const float*)d_in[6];
    const float* sigmas1  = (const float*)d_in[7];
    const float* centres1 = (const float*)d_in[8];
    float* out = (float*)d_out;

    const int B = in_sizes[1] / N_;           // 4
    dim3 grid(B * N_), block(256);            // 1 atom per block, 4 waves
    desc_kernel<<<grid, block, 0, stream>>>(numbers, coords, nuww0, sigmas0,
                                            centres0, nuww1, sigmas1, centres1, out);
}